// Round 7
// baseline (211.404 us; speedup 1.0000x reference)
//
#include <hip/hip_runtime.h>
#include <hip/hip_bf16.h>
#include <stdint.h>

#define B_ 8
#define H_ 8
#define S_ 512
#define K_ 64
#define NMB_ 4
#define NG_ 5

typedef unsigned short u16;
typedef __attribute__((ext_vector_type(8))) short short8;   // 8 x bf16 bits (4 VGPRs)
typedef __attribute__((ext_vector_type(4))) float f32x4;

// ---- workspace layout (bytes) ----
#define OFF_PERM 0                       // B_*S_*4 = 16 KB
#define OFF_WST  16384                   // H_*NG_*10*64*32*2 = 1.31 MB
#define OFF_MF   (1 << 21)               // 2 MB; M_frag: B_*H_*16*320*32*2 = 20.97 MB

// LDS staging: Mf kt-slab stored at row stride 80 B (40 u16) -> 2-way-only bank
// aliasing on ds_read_b128 (free per m136). One buffer = 320*40 u16 = 12800.
#define LDSBUF 12800

__device__ __forceinline__ u16 f2b(float f) {
    __hip_bfloat16 h = __float2bfloat16(f);
    return *reinterpret_cast<u16*>(&h);
}
__device__ __forceinline__ int clamp5(int g) {
    g = g < 0 ? 0 : g;
    return g > (NG_ - 1) ? (NG_ - 1) : g;
}

// ---------------- per-b counting sort of rows by b_seq class ----------------
__global__ void k_sort(const int* __restrict__ b_seq, int* __restrict__ perm) {
    const int b = blockIdx.x;
    const int lane = threadIdx.x;            // 64 threads = 1 wave
    const int* bs = b_seq + b * S_;

    int tot[NG_] = {0,0,0,0,0};
    for (int ch = 0; ch < S_ / 64; ++ch) {
        int g = clamp5(bs[ch * 64 + lane]);
        for (int bin = 0; bin < NG_; ++bin) {
            unsigned long long m = __ballot(g == bin);
            tot[bin] += (int)__popcll(m);
        }
    }
    int starts[NG_]; int run = 0;
    for (int bin = 0; bin < NG_; ++bin) { starts[bin] = run; run += tot[bin]; }

    int running[NG_] = {0,0,0,0,0};
    unsigned long long lt = (1ull << lane) - 1ull;
    for (int ch = 0; ch < S_ / 64; ++ch) {
        int i = ch * 64 + lane;
        int g = clamp5(bs[i]);
        int pos = 0;
        for (int bin = 0; bin < NG_; ++bin) {
            unsigned long long m = __ballot(g == bin);
            if (g == bin) pos = starts[bin] + running[bin] + (int)__popcll(m & lt);
            running[bin] += (int)__popcll(m);
        }
        perm[b * S_ + pos] = i;
    }
}

// ---- Wstack[h][bi][kt][D][kk] = W2_[c(bi,g),h,d,D], B-frag swizzled bf16; fp32 in ----
__global__ void k_w2s(const float* __restrict__ W2, const float* __restrict__ al,
                      u16* __restrict__ Wst) {
    const int h = blockIdx.x / NG_, bi = blockIdx.x % NG_;
    float sm[NG_][NMB_];
#pragma unroll
    for (int g = 0; g < NG_; ++g) {
        int c = (bi == 0 || g == 0) ? 0 : (bi - 1) * NMB_ + g;
        float a[NMB_]; float mx = -1e30f;
#pragma unroll
        for (int m = 0; m < NMB_; ++m) { a[m] = al[(c * NMB_ + m) * H_ + h]; mx = fmaxf(mx, a[m]); }
        float s = 0.f;
#pragma unroll
        for (int m = 0; m < NMB_; ++m) { a[m] = __expf(a[m] - mx); s += a[m]; }
        float inv = 1.f / s;
#pragma unroll
        for (int m = 0; m < NMB_; ++m) sm[g][m] = a[m] * inv;
    }
    for (int e = threadIdx.x; e < 320 * 64; e += 256) {
        int k = e >> 6, D = e & 63;
        int g = k >> 6, d = k & 63;
        float acc = 0.f;
#pragma unroll
        for (int m = 0; m < NMB_; ++m)
            acc += sm[g][m] * W2[((m * H_ + h) * K_ + d) * K_ + D];
        int kt = k >> 5, kk = k & 31;
        Wst[(((h * NG_ + bi) * 10 + kt) * 64 + D) * 32 + kk] = f2b(acc);
    }
}

// ---- M_frag build, V staged in LDS (each V element read from HBM exactly once) ----
// Mf[b][h][kt][n][kk] = (b_seq[j]==g ? v[j,d] : 0); n = g*64+d, j = kt*32+kk.
__global__ void k_buildM(const float* __restrict__ V, const int* __restrict__ b_seq,
                         u16* __restrict__ Mf) {
    __shared__ float vs[32 * 64];            // 8 KB: V[j0..j0+32][0..64]
    const int kt = blockIdx.x, h = blockIdx.y, b = blockIdx.z;
    const int bh = b * H_ + h;
    const int tid = threadIdx.x;             // 256
    const int c = tid & 3;                   // kk-chunk: kk = c*8 + q

    const float* vsrc = V + ((size_t)bh * S_ + kt * 32) * K_;
    *reinterpret_cast<float4*>(&vs[tid * 4])        = *reinterpret_cast<const float4*>(vsrc + tid * 4);
    *reinterpret_cast<float4*>(&vs[1024 + tid * 4]) = *reinterpret_cast<const float4*>(vsrc + 1024 + tid * 4);

    int gj[8];
#pragma unroll
    for (int q = 0; q < 8; ++q)
        gj[q] = clamp5(b_seq[b * S_ + kt * 32 + c * 8 + q]);
    __syncthreads();

#pragma unroll
    for (int it = 0; it < 5; ++it) {
        const int u = it * 256 + tid;        // 0..1279
        const int n = u >> 2;                // 0..319
        const int g = n >> 6, d = n & 63;
        u16 o[8];
#pragma unroll
        for (int q = 0; q < 8; ++q) {
            float v = vs[(c * 8 + q) * 64 + d];
            o[q] = (gj[q] == g) ? f2b(v) : (u16)0;
        }
        uint4 w;
        w.x = (uint32_t)o[0] | ((uint32_t)o[1] << 16);
        w.y = (uint32_t)o[2] | ((uint32_t)o[3] << 16);
        w.z = (uint32_t)o[4] | ((uint32_t)o[5] << 16);
        w.w = (uint32_t)o[6] | ((uint32_t)o[7] << 16);
        *reinterpret_cast<uint4*>(Mf + (((size_t)bh * 16 + kt) * 320 + n) * 32 + c * 8) = w;
    }
}

// ---- fused GEMM: canonical double-buffered K-loop ----
// Block = 4 waves = 64 rows (wave w owns 16-row tile). Per kt the block stages the
// 20 KB Mf slab into LDS (swizzled stride-80B), double-buffered; A prefetched in regs.
__global__ __launch_bounds__(256, 2) void k_main(const float* __restrict__ P,
                                                 const int* __restrict__ b_seq,
                                                 const int* __restrict__ perm,
                                                 const u16* __restrict__ Mf,
                                                 const u16* __restrict__ Wst,
                                                 float* __restrict__ out) {
    __shared__ __align__(16) u16 smem[2 * LDSBUF];   // 51.2 KB; st tiles alias after barrier
    const int b = blockIdx.z, h = blockIdx.y;
    const int w = threadIdx.y;                       // 0..3: wave = one 16-row tile
    const int lane = threadIdx.x;
    const int tid = w * 64 + lane;
    const int r16 = lane & 15, quad = lane >> 4;
    const int tile = blockIdx.x * 4 + w;             // 0..31
    const int bh = b * H_ + h;

    const int vi  = perm[b * S_ + tile * 16 + r16] & (S_ - 1);
    const int vbi = clamp5(b_seq[b * S_ + vi]);

    const u16* slab0 = Mf + ((size_t)bh * 16) * 10240;   // kt slabs: +kt*10240 u16
    const float* aP = P + ((size_t)bh * S_ + vi) * S_ + quad * 8;

    // ---- prologue: stage kt=0 slab, load A(0) ----
    {
        uint4 g0[5];
#pragma unroll
        for (int s = 0; s < 5; ++s)
            g0[s] = *reinterpret_cast<const uint4*>(slab0 + (size_t)(s * 256 + tid) * 8);
#pragma unroll
        for (int s = 0; s < 5; ++s) {
            int u = s * 256 + tid;
            *reinterpret_cast<uint4*>(smem + (u >> 2) * 40 + (u & 3) * 8) = g0[s];
        }
    }
    float4 ax = *reinterpret_cast<const float4*>(aP);
    float4 ay = *reinterpret_cast<const float4*>(aP + 4);
    __syncthreads();

    f32x4 acc1[20];
#pragma unroll
    for (int nt = 0; nt < 20; ++nt) acc1[nt] = (f32x4){0.f, 0.f, 0.f, 0.f};

#pragma unroll 2
    for (int kt = 0; kt < 16; ++kt) {
        // prefetch kt+1 (global loads in flight across the MFMA block)
        uint4 gn[5]; float4 axn, ayn;
        if (kt < 15) {
            const u16* src = slab0 + (size_t)(kt + 1) * 10240;
#pragma unroll
            for (int s = 0; s < 5; ++s)
                gn[s] = *reinterpret_cast<const uint4*>(src + (size_t)(s * 256 + tid) * 8);
            axn = *reinterpret_cast<const float4*>(aP + (kt + 1) * 32);
            ayn = *reinterpret_cast<const float4*>(aP + (kt + 1) * 32 + 4);
        }
        // A fragment (fp32 -> bf16)
        short8 afrag;
        afrag[0] = (short)f2b(ax.x); afrag[1] = (short)f2b(ax.y);
        afrag[2] = (short)f2b(ax.z); afrag[3] = (short)f2b(ax.w);
        afrag[4] = (short)f2b(ay.x); afrag[5] = (short)f2b(ay.y);
        afrag[6] = (short)f2b(ay.z); afrag[7] = (short)f2b(ay.w);
        const u16* buf = smem + (kt & 1) * LDSBUF;
#pragma unroll
        for (int nt = 0; nt < 20; ++nt) {
            int n = nt * 16 + r16;
            short8 bfrag = *reinterpret_cast<const short8*>(buf + n * 40 + quad * 8);
            acc1[nt] = __builtin_amdgcn_mfma_f32_16x16x32_bf16(afrag, bfrag, acc1[nt], 0, 0, 0);
        }
        if (kt < 15) {
            u16* bufn = smem + ((kt + 1) & 1) * LDSBUF;
#pragma unroll
            for (int s = 0; s < 5; ++s) {
                int u = s * 256 + tid;
                *reinterpret_cast<uint4*>(bufn + (u >> 2) * 40 + (u & 3) * 8) = gn[s];
            }
            __syncthreads();
            ax = axn; ay = ayn;
        }
    }
    __syncthreads();   // all waves done reading buf1 before st tiles alias it

    // ---- C-layout -> A-layout via LDS (bf16); per-wave private tile ----
    u16* st = smem + w * (16 * 328);
#pragma unroll
    for (int nt = 0; nt < 20; ++nt)
#pragma unroll
        for (int r = 0; r < 4; ++r) {
            int row = quad * 4 + r;                  // C/D: row=(lane>>4)*4+reg, col=lane&15
            st[row * 328 + nt * 16 + r16] = f2b(acc1[nt][r]);
        }
    // no barrier needed: stage 2 reads only this wave's tile

    // ---- stage 2: out rows = st_tile @ Wstack[blk] ----
    int blo = __shfl(vbi, 0), bhi = __shfl(vbi, 15);   // sorted => contiguous classes
    if (bhi < blo) bhi = blo;
    for (int blk = blo; blk <= bhi; ++blk) {
        f32x4 acc2[4];
#pragma unroll
        for (int nt = 0; nt < 4; ++nt) acc2[nt] = (f32x4){0.f, 0.f, 0.f, 0.f};
        const u16* wb = Wst + ((size_t)(h * NG_ + blk) * 10) * 2048 + r16 * 32 + quad * 8;
        for (int kt = 0; kt < 10; ++kt) {
            short8 a2 = *reinterpret_cast<const short8*>(&st[r16 * 328 + kt * 32 + quad * 8]);
#pragma unroll
            for (int nt = 0; nt < 4; ++nt) {
                short8 b2 = *reinterpret_cast<const short8*>(wb + kt * 2048 + nt * 512);
                acc2[nt] = __builtin_amdgcn_mfma_f32_16x16x32_bf16(a2, b2, acc2[nt], 0, 0, 0);
            }
        }
#pragma unroll
        for (int r = 0; r < 4; ++r) {
            int row = quad * 4 + r;
            int bir = __shfl(vbi, row);
            int ir  = __shfl(vi, row);
            if (bir == blk) {
#pragma unroll
                for (int nt = 0; nt < 4; ++nt)
                    out[((size_t)bh * S_ + ir) * K_ + nt * 16 + r16] = acc2[nt][r];
            }
        }
    }
}

// ---------------- launcher ----------------
extern "C" void kernel_launch(void* const* d_in, const int* in_sizes, int n_in,
                              void* d_out, int out_size, void* d_ws, size_t ws_size,
                              hipStream_t stream) {
    const float* p_attn = (const float*)d_in[0];
    const float* value  = (const float*)d_in[1];
    const int*   b_seq  = (const int*)d_in[2];
    const float* W2     = (const float*)d_in[3];
    const float* alpha2 = (const float*)d_in[4];

    char* ws = (char*)d_ws;
    int* perm = (int*)(ws + OFF_PERM);
    u16* Wst  = (u16*)(ws + OFF_WST);
    u16* Mf   = (u16*)(ws + OFF_MF);

    hipLaunchKernelGGL(k_sort, dim3(B_), dim3(64), 0, stream, b_seq, perm);
    hipLaunchKernelGGL(k_w2s, dim3(H_ * NG_), dim3(256), 0, stream, W2, alpha2, Wst);
    hipLaunchKernelGGL(k_buildM, dim3(16, H_, B_), dim3(256), 0, stream, value, b_seq, Mf);
    hipLaunchKernelGGL(k_main, dim3(8, H_, B_), dim3(64, 4), 0, stream,
                       p_attn, b_seq, perm, Mf, Wst, (float*)d_out);
}

// Round 8
// 160.080 us; speedup vs baseline: 1.3206x; 1.3206x over previous
//
#include <hip/hip_runtime.h>
#include <hip/hip_bf16.h>
#include <stdint.h>

#define B_ 8
#define H_ 8
#define S_ 512
#define K_ 64
#define NMB_ 4
#define NG_ 5

typedef unsigned short u16;
typedef __attribute__((ext_vector_type(8))) short short8;   // 8 x bf16 bits (4 VGPRs)
typedef __attribute__((ext_vector_type(4))) float f32x4;

// ---- workspace layout (bytes) ----
#define OFF_PERM 0                       // B_*S_*4 = 16 KB
#define OFF_WST  16384                   // H_*NG_*10*64*32*2 = 1.31 MB

// ---- k_main LDS map (u16 units) ----
#define VT_STRIDE 520                    // 512 + 8 pad: spreads banks for b128 reads
#define VT_U16    (64 * VT_STRIDE)       // 33280 u16 = 66560 B
#define MP_U16    (320 * 8)              // 16kt x 5g x 4quad mask short8s = 5120 B
// st tiles (4 x 16x328 = 20992 u16) alias the vT region after a barrier.

__device__ __forceinline__ u16 f2b(float f) {
    __hip_bfloat16 h = __float2bfloat16(f);
    return *reinterpret_cast<u16*>(&h);
}
__device__ __forceinline__ int clamp5(int g) {
    g = g < 0 ? 0 : g;
    return g > (NG_ - 1) ? (NG_ - 1) : g;
}
__device__ __forceinline__ short8 and8(short8 a, short8 m) {
    int4 x = *reinterpret_cast<int4*>(&a);
    int4 y = *reinterpret_cast<int4*>(&m);
    int4 r = make_int4(x.x & y.x, x.y & y.y, x.z & y.z, x.w & y.w);
    return *reinterpret_cast<short8*>(&r);
}

// ---------------- per-b counting sort of rows by b_seq class ----------------
__global__ void k_sort(const int* __restrict__ b_seq, int* __restrict__ perm) {
    const int b = blockIdx.x;
    const int lane = threadIdx.x;            // 64 threads = 1 wave
    const int* bs = b_seq + b * S_;

    int tot[NG_] = {0,0,0,0,0};
    for (int ch = 0; ch < S_ / 64; ++ch) {
        int g = clamp5(bs[ch * 64 + lane]);
        for (int bin = 0; bin < NG_; ++bin) {
            unsigned long long m = __ballot(g == bin);
            tot[bin] += (int)__popcll(m);
        }
    }
    int starts[NG_]; int run = 0;
    for (int bin = 0; bin < NG_; ++bin) { starts[bin] = run; run += tot[bin]; }

    int running[NG_] = {0,0,0,0,0};
    unsigned long long lt = (1ull << lane) - 1ull;
    for (int ch = 0; ch < S_ / 64; ++ch) {
        int i = ch * 64 + lane;
        int g = clamp5(bs[i]);
        int pos = 0;
        for (int bin = 0; bin < NG_; ++bin) {
            unsigned long long m = __ballot(g == bin);
            if (g == bin) pos = starts[bin] + running[bin] + (int)__popcll(m & lt);
            running[bin] += (int)__popcll(m);
        }
        perm[b * S_ + pos] = i;
    }
}

// ---- Wstack[h][bi][kt][D][kk] = W2_[c(bi,g),h,d,D], B-frag swizzled bf16; fp32 in ----
__global__ void k_w2s(const float* __restrict__ W2, const float* __restrict__ al,
                      u16* __restrict__ Wst) {
    const int h = blockIdx.x / NG_, bi = blockIdx.x % NG_;
    float sm[NG_][NMB_];
#pragma unroll
    for (int g = 0; g < NG_; ++g) {
        int c = (bi == 0 || g == 0) ? 0 : (bi - 1) * NMB_ + g;
        float a[NMB_]; float mx = -1e30f;
#pragma unroll
        for (int m = 0; m < NMB_; ++m) { a[m] = al[(c * NMB_ + m) * H_ + h]; mx = fmaxf(mx, a[m]); }
        float s = 0.f;
#pragma unroll
        for (int m = 0; m < NMB_; ++m) { a[m] = __expf(a[m] - mx); s += a[m]; }
        float inv = 1.f / s;
#pragma unroll
        for (int m = 0; m < NMB_; ++m) sm[g][m] = a[m] * inv;
    }
    for (int e = threadIdx.x; e < 320 * 64; e += 256) {
        int k = e >> 6, D = e & 63;
        int g = k >> 6, d = k & 63;
        float acc = 0.f;
#pragma unroll
        for (int m = 0; m < NMB_; ++m)
            acc += sm[g][m] * W2[((m * H_ + h) * K_ + d) * K_ + D];
        int kt = k >> 5, kk = k & 31;
        Wst[(((h * NG_ + bi) * 10 + kt) * 64 + D) * 32 + kk] = f2b(acc);
    }
}

// ---- fused: stage V^T + masks in LDS once; barrier-free masked-MFMA K-loop;
//      then st -> stage-2 MFMA vs Wstack. No Mf tensor, no double-buffer. ----
__global__ __launch_bounds__(256) void k_main(const float* __restrict__ P,
                                              const float* __restrict__ V,
                                              const int* __restrict__ b_seq,
                                              const int* __restrict__ perm,
                                              const u16* __restrict__ Wst,
                                              float* __restrict__ out) {
    __shared__ __align__(16) u16 smem[VT_U16 + MP_U16];
    u16* vT = smem;                         // vT[d][j], row stride VT_STRIDE
    u16* mp = smem + VT_U16;                // maskpack[((kt*5+g)*4+quad)*8 .. +8]
    const int b = blockIdx.z, h = blockIdx.y;
    const int w = threadIdx.y;              // wave = one 16-row tile
    const int lane = threadIdx.x;
    const int tid = w * 64 + lane;
    const int r16 = lane & 15, quad = lane >> 4;
    const int tile = blockIdx.x * 4 + w;    // 0..31
    const int bh = b * H_ + h;

    // ---- stage V^T (fp32 -> bf16 transpose) ----
    const float* vsrc = V + (size_t)bh * S_ * K_;
#pragma unroll
    for (int c = 0; c < 32; ++c) {
        int e = c * 1024 + tid * 4;         // 0..32767, coalesced float4
        int j = e >> 6, d = e & 63;
        float4 v = *reinterpret_cast<const float4*>(vsrc + e);
        vT[(d + 0) * VT_STRIDE + j] = f2b(v.x);
        vT[(d + 1) * VT_STRIDE + j] = f2b(v.y);
        vT[(d + 2) * VT_STRIDE + j] = f2b(v.z);
        vT[(d + 3) * VT_STRIDE + j] = f2b(v.w);
    }
    // ---- stage mask fragments: 0xFFFF where b_seq[k]==g ----
    for (int e = tid; e < 320; e += 256) {
        int kt = e / 20, rem = e % 20, g = rem >> 2, q = rem & 3;
        uint32_t dw[4];
#pragma unroll
        for (int t = 0; t < 4; ++t) {
            int k = kt * 32 + q * 8 + t * 2;
            uint32_t lo = (clamp5(b_seq[b * S_ + k])     == g) ? 0xFFFFu : 0u;
            uint32_t hi = (clamp5(b_seq[b * S_ + k + 1]) == g) ? 0xFFFF0000u : 0u;
            dw[t] = lo | hi;
        }
        *reinterpret_cast<uint4*>(mp + e * 8) = make_uint4(dw[0], dw[1], dw[2], dw[3]);
    }
    const int vi  = perm[b * S_ + tile * 16 + r16] & (S_ - 1);
    const int vbi = clamp5(b_seq[b * S_ + vi]);
    __syncthreads();

    // ---- stage 1: acc1[g*4+dt] (16x320) = P[rows,:] @ (V masked per g) ----
    f32x4 acc1[20];
#pragma unroll
    for (int nt = 0; nt < 20; ++nt) acc1[nt] = (f32x4){0.f, 0.f, 0.f, 0.f};

    const float* aP = P + ((size_t)bh * S_ + vi) * S_ + quad * 8;
    float4 ax = *reinterpret_cast<const float4*>(aP);
    float4 ay = *reinterpret_cast<const float4*>(aP + 4);
    for (int kt = 0; kt < 16; ++kt) {
        float4 axn, ayn;                    // prefetch next A (2 regs groups only)
        if (kt < 15) {
            axn = *reinterpret_cast<const float4*>(aP + (kt + 1) * 32);
            ayn = *reinterpret_cast<const float4*>(aP + (kt + 1) * 32 + 4);
        }
        short8 afrag;
        afrag[0] = (short)f2b(ax.x); afrag[1] = (short)f2b(ax.y);
        afrag[2] = (short)f2b(ax.z); afrag[3] = (short)f2b(ax.w);
        afrag[4] = (short)f2b(ay.x); afrag[5] = (short)f2b(ay.y);
        afrag[6] = (short)f2b(ay.z); afrag[7] = (short)f2b(ay.w);
        short8 vf[4];
#pragma unroll
        for (int dt = 0; dt < 4; ++dt)
            vf[dt] = *reinterpret_cast<const short8*>(
                &vT[(dt * 16 + r16) * VT_STRIDE + kt * 32 + quad * 8]);
#pragma unroll
        for (int g = 0; g < NG_; ++g) {
            short8 mk = *reinterpret_cast<const short8*>(mp + ((kt * 5 + g) * 4 + quad) * 8);
#pragma unroll
            for (int dt = 0; dt < 4; ++dt) {
                short8 bfrag = and8(vf[dt], mk);
                acc1[g * 4 + dt] =
                    __builtin_amdgcn_mfma_f32_16x16x32_bf16(afrag, bfrag, acc1[g * 4 + dt], 0, 0, 0);
            }
        }
        ax = axn; ay = ayn;
    }
    __syncthreads();   // all waves done reading vT before st tiles alias it

    // ---- C-layout -> A-layout via LDS (bf16); per-wave private tile ----
    u16* st = smem + w * (16 * 328);
#pragma unroll
    for (int nt = 0; nt < 20; ++nt)
#pragma unroll
        for (int r = 0; r < 4; ++r) {
            int row = quad * 4 + r;                  // C/D: row=(lane>>4)*4+reg, col=lane&15
            st[row * 328 + nt * 16 + r16] = f2b(acc1[nt][r]);
        }

    // ---- stage 2: out rows = st_tile @ Wstack[blk] ----
    int blo = __shfl(vbi, 0), bhi = __shfl(vbi, 15);   // sorted => contiguous classes
    if (bhi < blo) bhi = blo;
    for (int blk = blo; blk <= bhi; ++blk) {
        f32x4 acc2[4];
#pragma unroll
        for (int nt = 0; nt < 4; ++nt) acc2[nt] = (f32x4){0.f, 0.f, 0.f, 0.f};
        const u16* wb = Wst + ((size_t)(h * NG_ + blk) * 10) * 2048 + r16 * 32 + quad * 8;
        for (int kt = 0; kt < 10; ++kt) {
            short8 a2 = *reinterpret_cast<const short8*>(&st[r16 * 328 + kt * 32 + quad * 8]);
#pragma unroll
            for (int nt = 0; nt < 4; ++nt) {
                short8 b2 = *reinterpret_cast<const short8*>(wb + kt * 2048 + nt * 512);
                acc2[nt] = __builtin_amdgcn_mfma_f32_16x16x32_bf16(a2, b2, acc2[nt], 0, 0, 0);
            }
        }
#pragma unroll
        for (int r = 0; r < 4; ++r) {
            int row = quad * 4 + r;
            int bir = __shfl(vbi, row);
            int ir  = __shfl(vi, row);
            if (bir == blk) {
#pragma unroll
                for (int nt = 0; nt < 4; ++nt)
                    out[((size_t)bh * S_ + ir) * K_ + nt * 16 + r16] = acc2[nt][r];
            }
        }
    }
}

// ---------------- launcher ----------------
extern "C" void kernel_launch(void* const* d_in, const int* in_sizes, int n_in,
                              void* d_out, int out_size, void* d_ws, size_t ws_size,
                              hipStream_t stream) {
    const float* p_attn = (const float*)d_in[0];
    const float* value  = (const float*)d_in[1];
    const int*   b_seq  = (const int*)d_in[2];
    const float* W2     = (const float*)d_in[3];
    const float* alpha2 = (const float*)d_in[4];

    char* ws = (char*)d_ws;
    int* perm = (int*)(ws + OFF_PERM);
    u16* Wst  = (u16*)(ws + OFF_WST);

    hipLaunchKernelGGL(k_sort, dim3(B_), dim3(64), 0, stream, b_seq, perm);
    hipLaunchKernelGGL(k_w2s, dim3(H_ * NG_), dim3(256), 0, stream, W2, alpha2, Wst);
    hipLaunchKernelGGL(k_main, dim3(8, H_, B_), dim3(64, 4), 0, stream,
                       p_attn, value, b_seq, perm, Wst, (float*)d_out);
}

// Round 10
// 152.273 us; speedup vs baseline: 1.3883x; 1.0513x over previous
//
#include <hip/hip_runtime.h>
#include <hip/hip_bf16.h>
#include <stdint.h>

#define B_ 8
#define H_ 8
#define S_ 512
#define K_ 64
#define NMB_ 4
#define NG_ 5

typedef unsigned short u16;
typedef __attribute__((ext_vector_type(8))) short short8;   // 8 x bf16 bits (4 VGPRs)
typedef __attribute__((ext_vector_type(4))) float f32x4;

// ---- workspace layout (bytes) ----
#define OFF_PERM 0                        // B_*S_*4 = 16384
#define OFF_WST  16384                    // Wst: 40*10*64*32*2 = 1,638,400 -> ends 1,654,784
#define OFF_VTF  1654784                  // bf16 vTf: 64*4*16*16*32*2 = 4,194,304
// R8 BUG (fixed): OFF_VTF was 1327104, inside Wst -> heads 6-7 weights raced with vTf.

// ---- k_main LDS (u16 units): st tiles + mask fragments (no V staging) ----
#define ST_U16 (4 * 16 * 328)             // 20992 u16 = 41984 B
#define MP_U16 (320 * 8)                  // 2560 u16  =  5120 B

__device__ __forceinline__ u16 f2b(float f) {
    __hip_bfloat16 h = __float2bfloat16(f);
    return *reinterpret_cast<u16*>(&h);
}
__device__ __forceinline__ int clamp5(int g) {
    g = g < 0 ? 0 : g;
    return g > (NG_ - 1) ? (NG_ - 1) : g;
}
__device__ __forceinline__ short8 and8(short8 a, short8 m) {
    int4 x = *reinterpret_cast<int4*>(&a);
    int4 y = *reinterpret_cast<int4*>(&m);
    int4 r = make_int4(x.x & y.x, x.y & y.y, x.z & y.z, x.w & y.w);
    return *reinterpret_cast<short8*>(&r);
}

// ================= fused prep: sort (bx 0..7) | w2s (bx 8..47) | vT build (bx 48..111) ====
__global__ __launch_bounds__(256) void k_prep(const float* __restrict__ V,
                                              const int* __restrict__ b_seq,
                                              const float* __restrict__ W2,
                                              const float* __restrict__ al,
                                              int* __restrict__ perm,
                                              u16* __restrict__ Wst,
                                              u16* __restrict__ vTf) {
    __shared__ u16 vs[128 * 72];             // 18.4 KB, used by vT branch only
    const int bx = blockIdx.x;
    const int tid = threadIdx.x;

    if (bx < 8) {
        // ---- per-b counting sort of rows by class (wave 0 only) ----
        if (tid >= 64) return;
        const int b = bx, lane = tid;
        const int* bs = b_seq + b * S_;
        int tot[NG_] = {0,0,0,0,0};
        for (int ch = 0; ch < S_ / 64; ++ch) {
            int g = clamp5(bs[ch * 64 + lane]);
            for (int bin = 0; bin < NG_; ++bin) {
                unsigned long long m = __ballot(g == bin);
                tot[bin] += (int)__popcll(m);
            }
        }
        int starts[NG_]; int run = 0;
        for (int bin = 0; bin < NG_; ++bin) { starts[bin] = run; run += tot[bin]; }
        int running[NG_] = {0,0,0,0,0};
        unsigned long long lt = (1ull << lane) - 1ull;
        for (int ch = 0; ch < S_ / 64; ++ch) {
            int i = ch * 64 + lane;
            int g = clamp5(bs[i]);
            int pos = 0;
            for (int bin = 0; bin < NG_; ++bin) {
                unsigned long long m = __ballot(g == bin);
                if (g == bin) pos = starts[bin] + running[bin] + (int)__popcll(m & lt);
                running[bin] += (int)__popcll(m);
            }
            perm[b * S_ + pos] = i;
        }
    } else if (bx < 48) {
        // ---- Wstack[h][bi][kt][D][kk] = W2_[c(bi,g),h,d,D], B-frag swizzled ----
        const int h = (bx - 8) / NG_, bi = (bx - 8) % NG_;
        float sm[NG_][NMB_];
#pragma unroll
        for (int g = 0; g < NG_; ++g) {
            int c = (bi == 0 || g == 0) ? 0 : (bi - 1) * NMB_ + g;
            float a[NMB_]; float mx = -1e30f;
#pragma unroll
            for (int m = 0; m < NMB_; ++m) { a[m] = al[(c * NMB_ + m) * H_ + h]; mx = fmaxf(mx, a[m]); }
            float s = 0.f;
#pragma unroll
            for (int m = 0; m < NMB_; ++m) { a[m] = __expf(a[m] - mx); s += a[m]; }
            float inv = 1.f / s;
#pragma unroll
            for (int m = 0; m < NMB_; ++m) sm[g][m] = a[m] * inv;
        }
        for (int e = tid; e < 320 * 64; e += 256) {
            int k = e >> 6, D = e & 63;
            int g = k >> 6, d = k & 63;
            float acc = 0.f;
#pragma unroll
            for (int m = 0; m < NMB_; ++m)
                acc += sm[g][m] * W2[((m * H_ + h) * K_ + d) * K_ + D];
            int kt = k >> 5, kk = k & 31;
            Wst[(((h * NG_ + bi) * 10 + kt) * 64 + D) * 32 + kk] = f2b(acc);
        }
    } else {
        // ---- vTf[bh][dt][kt][r16][quad*8+t] = bf16(V[bh][kt*32+quad*8+t][dt*16+r16]) ----
        const int bh = bx - 48;
        const float* vsrc = V + (size_t)bh * S_ * K_;
        u16* dst = vTf + (size_t)bh * 32768;
        for (int c = 0; c < 4; ++c) {        // j-chunk of 128
#pragma unroll
            for (int it = 0; it < 8; ++it) { // coalesced fp32 load -> bf16 LDS tile
                int f = (it * 256 + tid) * 4;          // 0..8191
                int jL = f >> 6, d = f & 63;
                float4 v = *reinterpret_cast<const float4*>(vsrc + (size_t)(c * 128 + jL) * 64 + d);
                uint2 pk;
                pk.x = (uint32_t)f2b(v.x) | ((uint32_t)f2b(v.y) << 16);
                pk.y = (uint32_t)f2b(v.z) | ((uint32_t)f2b(v.w) << 16);
                *reinterpret_cast<uint2*>(&vs[jL * 72 + d]) = pk;
            }
            __syncthreads();
#pragma unroll
            for (int it = 0; it < 4; ++it) { // transpose out, coalesced 16B stores
                int idx = it * 256 + tid;              // 0..1023
                int quad = idx & 3, r = (idx >> 2) & 15, ktL = (idx >> 6) & 3, dt = idx >> 8;
                int d = dt * 16 + r;
                u16 o[8];
#pragma unroll
                for (int t = 0; t < 8; ++t)
                    o[t] = vs[(ktL * 32 + quad * 8 + t) * 72 + d];
                uint4 w;
                w.x = (uint32_t)o[0] | ((uint32_t)o[1] << 16);
                w.y = (uint32_t)o[2] | ((uint32_t)o[3] << 16);
                w.z = (uint32_t)o[4] | ((uint32_t)o[5] << 16);
                w.w = (uint32_t)o[6] | ((uint32_t)o[7] << 16);
                int kt = c * 4 + ktL;
                *reinterpret_cast<uint4*>(dst + (size_t)((dt * 16 + kt) * 16 + r) * 32 + quad * 8) = w;
            }
            __syncthreads();
        }
    }
}

// ==== fused main: masked-MFMA stage 1 (B direct from global vTf, masks in LDS),
//      st -> stage-2 MFMA vs Wstack. No V staging, no double-buffer. ====
__global__ __launch_bounds__(256) void k_main(const float* __restrict__ P,
                                              const int* __restrict__ b_seq,
                                              const int* __restrict__ perm,
                                              const u16* __restrict__ vTf,
                                              const u16* __restrict__ Wst,
                                              float* __restrict__ out) {
    __shared__ __align__(16) u16 smem[ST_U16 + MP_U16];
    u16* st_all = smem;                      // 4 per-wave 16x328 tiles
    u16* mp = smem + ST_U16;                 // maskpack[((kt*5+g)*4+quad)*8 .. +8]
    const int b = blockIdx.z, h = blockIdx.y;
    const int w = threadIdx.y;               // wave = one 16-row tile
    const int lane = threadIdx.x;
    const int tid = w * 64 + lane;
    const int r16 = lane & 15, quad = lane >> 4;
    const int tile = blockIdx.x * 4 + w;     // 0..31
    const int bh = b * H_ + h;

    // ---- stage mask fragments: 0xFFFF where b_seq[k]==g ----
    for (int e = tid; e < 320; e += 256) {
        int kt = e / 20, rem = e % 20, g = rem >> 2, q = rem & 3;
        uint32_t dw[4];
#pragma unroll
        for (int t = 0; t < 4; ++t) {
            int k = kt * 32 + q * 8 + t * 2;
            uint32_t lo = (clamp5(b_seq[b * S_ + k])     == g) ? 0xFFFFu : 0u;
            uint32_t hi = (clamp5(b_seq[b * S_ + k + 1]) == g) ? 0xFFFF0000u : 0u;
            dw[t] = lo | hi;
        }
        *reinterpret_cast<uint4*>(mp + e * 8) = make_uint4(dw[0], dw[1], dw[2], dw[3]);
    }
    const int vi  = perm[b * S_ + tile * 16 + r16] & (S_ - 1);
    const int vbi = clamp5(b_seq[b * S_ + vi]);
    __syncthreads();

    // ---- stage 1: acc1[g*4+dt] (16x320) = P[rows,:] @ (V masked per g) ----
    f32x4 acc1[20];
#pragma unroll
    for (int nt = 0; nt < 20; ++nt) acc1[nt] = (f32x4){0.f, 0.f, 0.f, 0.f};

    const float* aP = P + ((size_t)bh * S_ + vi) * S_ + quad * 8;
    const u16* vb = vTf + (size_t)bh * 32768 + r16 * 32 + quad * 8;   // + dt*8192 + kt*512
    float4 ax = *reinterpret_cast<const float4*>(aP);
    float4 ay = *reinterpret_cast<const float4*>(aP + 4);
    for (int kt = 0; kt < 16; ++kt) {
        float4 axn, ayn;                     // A prefetch (small, no spill)
        if (kt < 15) {
            axn = *reinterpret_cast<const float4*>(aP + (kt + 1) * 32);
            ayn = *reinterpret_cast<const float4*>(aP + (kt + 1) * 32 + 4);
        }
        short8 vf[4];                        // B fragments direct from L2-hot vTf
#pragma unroll
        for (int dt = 0; dt < 4; ++dt)
            vf[dt] = *reinterpret_cast<const short8*>(vb + dt * 8192 + kt * 512);
        short8 afrag;
        afrag[0] = (short)f2b(ax.x); afrag[1] = (short)f2b(ax.y);
        afrag[2] = (short)f2b(ax.z); afrag[3] = (short)f2b(ax.w);
        afrag[4] = (short)f2b(ay.x); afrag[5] = (short)f2b(ay.y);
        afrag[6] = (short)f2b(ay.z); afrag[7] = (short)f2b(ay.w);
#pragma unroll
        for (int g = 0; g < NG_; ++g) {
            short8 mk = *reinterpret_cast<const short8*>(mp + ((kt * 5 + g) * 4 + quad) * 8);
#pragma unroll
            for (int dt = 0; dt < 4; ++dt) {
                short8 bfrag = and8(vf[dt], mk);
                acc1[g * 4 + dt] =
                    __builtin_amdgcn_mfma_f32_16x16x32_bf16(afrag, bfrag, acc1[g * 4 + dt], 0, 0, 0);
            }
        }
        ax = axn; ay = ayn;
    }

    // ---- C-layout -> A-layout via LDS (bf16); per-wave private tile, no barrier ----
    u16* st = st_all + w * (16 * 328);
#pragma unroll
    for (int nt = 0; nt < 20; ++nt)
#pragma unroll
        for (int r = 0; r < 4; ++r) {
            int row = quad * 4 + r;                  // C/D: row=(lane>>4)*4+reg, col=lane&15
            st[row * 328 + nt * 16 + r16] = f2b(acc1[nt][r]);
        }

    // ---- stage 2: out rows = st_tile @ Wstack[blk] ----
    int blo = __shfl(vbi, 0), bhi = __shfl(vbi, 15);   // sorted => contiguous classes
    if (bhi < blo) bhi = blo;
    for (int blk = blo; blk <= bhi; ++blk) {
        f32x4 acc2[4];
#pragma unroll
        for (int nt = 0; nt < 4; ++nt) acc2[nt] = (f32x4){0.f, 0.f, 0.f, 0.f};
        const u16* wb = Wst + ((size_t)(h * NG_ + blk) * 10) * 2048 + r16 * 32 + quad * 8;
        for (int kt = 0; kt < 10; ++kt) {
            short8 a2 = *reinterpret_cast<const short8*>(&st[r16 * 328 + kt * 32 + quad * 8]);
#pragma unroll
            for (int nt = 0; nt < 4; ++nt) {
                short8 b2 = *reinterpret_cast<const short8*>(wb + kt * 2048 + nt * 512);
                acc2[nt] = __builtin_amdgcn_mfma_f32_16x16x32_bf16(a2, b2, acc2[nt], 0, 0, 0);
            }
        }
#pragma unroll
        for (int r = 0; r < 4; ++r) {
            int row = quad * 4 + r;
            int bir = __shfl(vbi, row);
            int ir  = __shfl(vi, row);
            if (bir == blk) {
#pragma unroll
                for (int nt = 0; nt < 4; ++nt)
                    out[((size_t)bh * S_ + ir) * K_ + nt * 16 + r16] = acc2[nt][r];
            }
        }
    }
}

// ---------------- launcher ----------------
extern "C" void kernel_launch(void* const* d_in, const int* in_sizes, int n_in,
                              void* d_out, int out_size, void* d_ws, size_t ws_size,
                              hipStream_t stream) {
    const float* p_attn = (const float*)d_in[0];
    const float* value  = (const float*)d_in[1];
    const int*   b_seq  = (const int*)d_in[2];
    const float* W2     = (const float*)d_in[3];
    const float* alpha2 = (const float*)d_in[4];

    char* ws = (char*)d_ws;
    int* perm = (int*)(ws + OFF_PERM);
    u16* Wst  = (u16*)(ws + OFF_WST);
    u16* vTf  = (u16*)(ws + OFF_VTF);

    hipLaunchKernelGGL(k_prep, dim3(112), dim3(256), 0, stream,
                       value, b_seq, W2, alpha2, perm, Wst, vTf);
    hipLaunchKernelGGL(k_main, dim3(8, H_, B_), dim3(64, 4), 0, stream,
                       p_attn, b_seq, perm, vTf, Wst, (float*)d_out);
}